// Round 9
// baseline (1417.985 us; speedup 1.0000x reference)
//
#include <hip/hip_runtime.h>
#include <math.h>

#define T_LEN   1024
#define S_SEAS  168
#define H_SZ    128
#define G_SZ    512   // 4*H
#define WIN_SZ  168
#define OUT_SZ  24
#define N_WIN   833
#define BB      16
#define NBLK    ((N_WIN + BB - 1) / BB)   // 53

typedef __attribute__((ext_vector_type(8))) __bf16 bf16x8;
typedef __attribute__((ext_vector_type(4))) float  f32x4;

__device__ __forceinline__ float fsig(float x) {
    return __fdividef(1.0f, 1.0f + __expf(-x));
}
__device__ __forceinline__ float ftanh(float x) {
    return 1.0f - __fdividef(2.0f, __expf(2.0f * x) + 1.0f);
}

// Counted-wait barrier: order LDS only; globals ride across (T3/T4).
#define LDS_BARRIER()                                        \
    do {                                                     \
        asm volatile("s_waitcnt lgkmcnt(0)" ::: "memory");   \
        __builtin_amdgcn_s_barrier();                        \
    } while (0)

// ---------------------------------------------------------------------------
// Kernel 1: es_scan (block 0) + weight prep (blocks 1..160).
// ---------------------------------------------------------------------------
__global__ __launch_bounds__(256) void pre_kernel(
    const float* __restrict__ x,
    const float* __restrict__ lvl_raw,
    const float* __restrict__ seas_raw,
    const float* __restrict__ seas_params,
    const float* __restrict__ Wh0,
    const float* __restrict__ Wx1,
    const float* __restrict__ Wh1,
    const float* __restrict__ tanhW,
    float* __restrict__ levels,
    float* __restrict__ wsv,
    uint4* __restrict__ pw0,
    uint4* __restrict__ pw1,
    float* __restrict__ tanhWT) {
    __shared__ float xl[T_LEN];
    __shared__ float buf[S_SEAS];
    const int t = threadIdx.x;

    if (blockIdx.x == 0) {
        for (int i = t; i < T_LEN; i += 256) xl[i] = x[i];
        for (int i = t; i < S_SEAS; i += 256) {
            const float w = expf(seas_params[i]);
            buf[i] = w;
            wsv[i] = w;
        }
        __syncthreads();
        if (t == 0) {
            const float a  = 1.0f / (1.0f + expf(-lvl_raw[0]));
            const float g  = 1.0f / (1.0f + expf(-seas_raw[0]));
            const float ca = 1.0f - a, cg = 1.0f - g;
            float level = __fdividef(xl[0], buf[0]);
            levels[0] = level;
            wsv[S_SEAS] = buf[0];   // ws_full[168] = w_init[0]

            float wq[8], tq[8];
#pragma unroll
            for (int k = 0; k < 8; ++k) {
                const int i = 1 + k;
                const float w = buf[i % S_SEAS];
                wq[k] = w;
                tq[k] = __fdividef(a * xl[i], w);
            }
            for (int i = 1; i < T_LEN; i += 8) {
#pragma unroll
                for (int s = 0; s < 8; ++s) {
                    const int ii = i + s;
                    if (ii >= T_LEN) break;
                    const float w  = wq[s];
                    const float nl = tq[s] + ca * level;   // chain: 1 FMA
                    const float nw = cg * w + __fdividef(g * xl[ii], nl);
                    levels[ii] = nl;
                    buf[ii % S_SEAS] = nw;
                    if (ii + S_SEAS < T_LEN) wsv[ii + S_SEAS] = nw;
                    level = nl;
                    const int i8 = ii + 8;
                    if (i8 < T_LEN) {
                        const float w8 = buf[i8 % S_SEAS];
                        wq[s] = w8;
                        tq[s] = __fdividef(a * xl[i8], w8);
                    }
                }
            }
        }
        return;
    }

    // ------- weight prep: pack MFMA B-frags (m92/m97 layout) -------
    const int idx = (blockIdx.x - 1) * 256 + t;
    auto bfr = [](float f) -> unsigned int {   // fp32 -> bf16 (RNE)
        union { float f; unsigned int u; } v; v.f = f;
        return ((v.u + 0x7FFFu + ((v.u >> 16) & 1u)) >> 16) & 0xFFFFu;
    };
    if (idx < 8192) {                       // pw0: Wh0, 128 frags (8w x 4ns x 4kt)
        const int l = idx & 63, f = idx >> 6;
        const int kt = f & 3, ns = (f >> 2) & 3, w = f >> 4;
        const int g = ns * 128 + w * 16 + (l & 15);
        const int kb = kt * 32 + (l >> 4) * 8;
        const float* s = Wh0 + g * H_SZ + kb;
        uint4 o;
        unsigned int* po = &o.x;
        for (int p = 0; p < 4; ++p) po[p] = bfr(s[2 * p]) | (bfr(s[2 * p + 1]) << 16);
        pw0[idx] = o;
    } else if (idx < 8192 + 16384) {        // pw1: [Wx1 (kt<4); Wh1 (kt>=4)]
        const int j = idx - 8192;
        const int l = j & 63, f = j >> 6;
        const int kt = f & 7, ns = (f >> 3) & 3, w = f >> 5;
        const int g = ns * 128 + w * 16 + (l & 15);
        const float* srcm = (kt < 4) ? Wx1 : Wh1;
        const int kb = (kt & 3) * 32 + (l >> 4) * 8;
        const float* s = srcm + g * H_SZ + kb;
        uint4 o;
        unsigned int* po = &o.x;
        for (int p = 0; p < 4; ++p) po[p] = bfr(s[2 * p]) | (bfr(s[2 * p + 1]) << 16);
        pw1[j] = o;
    } else if (idx < 8192 + 16384 + 16384) {  // tanh_W transpose (fp32)
        const int j = idx - 8192 - 16384;
        const int m = j >> 7, k = j & 127;
        tanhWT[k * H_SZ + m] = tanhW[j];
    }
}

// ---------------------------------------------------------------------------
// Kernel 2: fully fused 2-layer LSTM + window + head + labels.
// 16 waves (4/SIMD): waves 0-7 = layer-0 at step it; waves 8-15 = layer-1
// at step it-1. h0/h1 handoff via LDS double-buffers (NO global hs0).
// All weights AGPR-pinned (wW[4][8] = 128 AGPR/lane, uniform both roles).
// One counted-wait barrier per iteration; 169 iterations.
// ---------------------------------------------------------------------------
__global__
__attribute__((amdgpu_flat_work_group_size(1024, 1024), amdgpu_waves_per_eu(4, 4)))
void fused_kernel(
    const float* __restrict__ x,
    const float* __restrict__ levels,
    const float* __restrict__ wsv,
    const float* __restrict__ noise_in,
    const float* __restrict__ Wx0,
    const float* __restrict__ b0v,
    const float* __restrict__ b1v,
    const uint4* __restrict__ pw0,
    const uint4* __restrict__ pw1,
    const float* __restrict__ tanhWT,
    const float* __restrict__ tanhB,
    const float* __restrict__ linW,
    const float* __restrict__ linB,
    const float* __restrict__ noise_lab,
    float* __restrict__ out) {
    __shared__ __bf16 h0s[2][16 * 128];    // 8KB, swizzled, pitch 256B
    __shared__ __bf16 h1s[2][16 * 128];    // 8KB
    __shared__ float  xls[WIN_SZ][16];     // 10.75KB
    __shared__ float  hfl[16][129];        // 8.25KB final h1 (f32)
    __shared__ float  featl[16][128];      // 8KB tanh features

    const int tid  = threadIdx.x;
    const int wv   = tid >> 6;            // 0..15
    const int lane = tid & 63;
    const int cc   = lane & 15;
    const int kl   = lane >> 4;
    const int base = blockIdx.x * BB;
    const bool isL1 = (wv >= 8);
    const int w    = wv & 7;

    // stage x (fused log-deseasonalization + noise) for the 16 windows
    for (int i = tid; i < WIN_SZ * BB; i += 1024) {
        const int t = i >> 4, m = i & 15;
        const int nn = base + m;
        float v = 0.0f;
        if (nn < N_WIN) {
            const float lev = levels[nn + WIN_SZ];
            const int tt = nn + t;
            v = logf(x[tt] / (lev * wsv[tt])) + noise_in[nn * WIN_SZ + t];
        }
        xls[t][m] = v;
    }
    for (int i = tid; i < 2 * 16 * 128; i += 1024) {
        (&h0s[0][0])[i] = (__bf16)0.0f;
        (&h1s[0][0])[i] = (__bf16)0.0f;
    }

    // role-specific weights into uniform AGPR block wW[4][8]
    // l0: wW[ns][kt] = Wh0 frag (kt&3 duplicated into 4..7, unused)
    // l1: wW[ns][0..3] = Wx1, wW[ns][4..7] = Wh1
    const bf16x8* psrc = isL1 ? (const bf16x8*)pw1 : (const bf16x8*)pw0;
    bf16x8 wW[4][8];
#pragma unroll
    for (int ns = 0; ns < 4; ++ns)
#pragma unroll
        for (int kt = 0; kt < 8; ++kt) {
            const int fi = isL1 ? ((w * 4 + ns) * 8 + kt)
                                : ((w * 4 + ns) * 4 + (kt & 3));
            wW[ns][kt] = psrc[fi * 64 + lane];
        }
#pragma unroll
    for (int ns = 0; ns < 4; ++ns)
#pragma unroll
        for (int kt = 0; kt < 8; ++kt)
            asm("" : "+a"(wW[ns][kt]));   // pin in AGPR class (one-time)

    float br[4], wx0r[4];
#pragma unroll
    for (int ns = 0; ns < 4; ++ns) {
        const int g = ns * 128 + w * 16 + cc;
        br[ns]   = isL1 ? b1v[g] : b0v[g];
        wx0r[ns] = isL1 ? 0.0f : Wx0[g];
    }
    float cr[4] = {0.f, 0.f, 0.f, 0.f};

    // loop-invariant swizzled LDS byte offsets
    int rdA[4], wrA[4];
#pragma unroll
    for (int kt = 0; kt < 4; ++kt)
        rdA[kt] = cc * 256 + ((kt * 64 + kl * 16) ^ ((cc & 7) << 4));
#pragma unroll
    for (int r = 0; r < 4; ++r) {
        const int row = kl * 4 + r;
        wrA[r] = row * 256 + (((w * 16 + cc) * 2) ^ ((row & 7) << 4));
    }
    __syncthreads();   // one-time full barrier after init

    char* const hb0 = (char*)&h0s[0][0];
    char* const hb1 = (char*)&h1s[0][0];

    // Slot convention: h at time t lives in slot t&1 of its buffer.
    // Iteration it (parity P=it&1):
    //   l0 (it<168): reads h0[it-1] slot P^1, writes h0[it] slot P
    //   l1 (it>=1, t1=it-1): reads h0[t1] slot P^1, h1[t1-1] slot P,
    //                        writes h1[t1] slot P^1 (or hfl at t1=167)
#define FUSED_STEP(IT, P)                                                      \
    {                                                                          \
        const int it_ = (IT);                                                  \
        if (!isL1) {                                                           \
            if (it_ < WIN_SZ) {                                                \
                const float4 xt_ = *(const float4*)&xls[it_][kl * 4];          \
                const float xa_[4] = {xt_.x, xt_.y, xt_.z, xt_.w};             \
                f32x4 a0_, a1_, a2_, a3_;                                      \
                _Pragma("unroll")                                              \
                for (int r = 0; r < 4; ++r) {                                  \
                    a0_[r] = br[0] + wx0r[0] * xa_[r];                         \
                    a1_[r] = br[1] + wx0r[1] * xa_[r];                         \
                    a2_[r] = br[2] + wx0r[2] * xa_[r];                         \
                    a3_[r] = br[3] + wx0r[3] * xa_[r];                         \
                }                                                              \
                _Pragma("unroll")                                              \
                for (int kt = 0; kt < 4; ++kt) {                               \
                    const bf16x8 af_ = *(const bf16x8*)(hb0 + ((P) ^ 1) * 4096 + rdA[kt]); \
                    a0_ = __builtin_amdgcn_mfma_f32_16x16x32_bf16(af_, wW[0][kt], a0_, 0, 0, 0); \
                    a1_ = __builtin_amdgcn_mfma_f32_16x16x32_bf16(af_, wW[1][kt], a1_, 0, 0, 0); \
                    a2_ = __builtin_amdgcn_mfma_f32_16x16x32_bf16(af_, wW[2][kt], a2_, 0, 0, 0); \
                    a3_ = __builtin_amdgcn_mfma_f32_16x16x32_bf16(af_, wW[3][kt], a3_, 0, 0, 0); \
                }                                                              \
                _Pragma("unroll")                                              \
                for (int r = 0; r < 4; ++r) {                                  \
                    const float ig_ = fsig(a0_[r]);                            \
                    const float fg_ = fsig(a1_[r]);                            \
                    const float gg_ = ftanh(a2_[r]);                           \
                    const float og_ = fsig(a3_[r]);                            \
                    const float c_  = fg_ * cr[r] + ig_ * gg_;                 \
                    cr[r] = c_;                                                \
                    *(__bf16*)(hb0 + (P) * 4096 + wrA[r]) =                    \
                        (__bf16)(og_ * ftanh(c_));                             \
                }                                                              \
            }                                                                  \
        } else {                                                               \
            if (it_ >= 1) {                                                    \
                const int t1_ = it_ - 1;                                       \
                f32x4 a0_ = {br[0], br[0], br[0], br[0]};                      \
                f32x4 a1_ = {br[1], br[1], br[1], br[1]};                      \
                f32x4 a2_ = {br[2], br[2], br[2], br[2]};                      \
                f32x4 a3_ = {br[3], br[3], br[3], br[3]};                      \
                _Pragma("unroll")                                              \
                for (int kt = 0; kt < 4; ++kt) {  /* Wx1 on h0[t1] */          \
                    const bf16x8 af_ = *(const bf16x8*)(hb0 + ((P) ^ 1) * 4096 + rdA[kt]); \
                    a0_ = __builtin_amdgcn_mfma_f32_16x16x32_bf16(af_, wW[0][kt], a0_, 0, 0, 0); \
                    a1_ = __builtin_amdgcn_mfma_f32_16x16x32_bf16(af_, wW[1][kt], a1_, 0, 0, 0); \
                    a2_ = __builtin_amdgcn_mfma_f32_16x16x32_bf16(af_, wW[2][kt], a2_, 0, 0, 0); \
                    a3_ = __builtin_amdgcn_mfma_f32_16x16x32_bf16(af_, wW[3][kt], a3_, 0, 0, 0); \
                }                                                              \
                _Pragma("unroll")                                              \
                for (int kt = 0; kt < 4; ++kt) {  /* Wh1 on h1[t1-1] */        \
                    const bf16x8 af_ = *(const bf16x8*)(hb1 + (P) * 4096 + rdA[kt]); \
                    a0_ = __builtin_amdgcn_mfma_f32_16x16x32_bf16(af_, wW[0][kt + 4], a0_, 0, 0, 0); \
                    a1_ = __builtin_amdgcn_mfma_f32_16x16x32_bf16(af_, wW[1][kt + 4], a1_, 0, 0, 0); \
                    a2_ = __builtin_amdgcn_mfma_f32_16x16x32_bf16(af_, wW[2][kt + 4], a2_, 0, 0, 0); \
                    a3_ = __builtin_amdgcn_mfma_f32_16x16x32_bf16(af_, wW[3][kt + 4], a3_, 0, 0, 0); \
                }                                                              \
                _Pragma("unroll")                                              \
                for (int r = 0; r < 4; ++r) {                                  \
                    const float ig_ = fsig(a0_[r]);                            \
                    const float fg_ = fsig(a1_[r]);                            \
                    const float gg_ = ftanh(a2_[r]);                           \
                    const float og_ = fsig(a3_[r]);                            \
                    const float c_  = fg_ * cr[r] + ig_ * gg_;                 \
                    cr[r] = c_;                                                \
                    const float hv_ = og_ * ftanh(c_);                         \
                    if (t1_ == WIN_SZ - 1) {                                   \
                        hfl[kl * 4 + r][w * 16 + cc] = hv_;                    \
                    } else {                                                   \
                        *(__bf16*)(hb1 + ((P) ^ 1) * 4096 + wrA[r]) = (__bf16)hv_; \
                    }                                                          \
                }                                                              \
            }                                                                  \
        }                                                                      \
        LDS_BARRIER();                                                         \
    }

    for (int tp = 0; tp < WIN_SZ / 2; ++tp) {
        FUSED_STEP(2 * tp, 0)
        FUSED_STEP(2 * tp + 1, 1)
    }
    FUSED_STEP(WIN_SZ, 0)   // it=168: l1 finishes t1=167 -> hfl
#undef FUSED_STEP

    // ---- epilogue: feat = tanh(h @ tanhW^T + tanhB) ----
    for (int p = tid; p < BB * H_SZ; p += 1024) {
        const int m = p >> 7, u = p & 127;
        float acc = tanhB[u];
        for (int k = 0; k < H_SZ; ++k)
            acc += hfl[m][k] * tanhWT[k * H_SZ + u];
        featl[m][u] = tanhf(acc);
    }
    LDS_BARRIER();

    // ---- out = feat @ linW^T + linB; labels ----
    for (int p = tid; p < BB * OUT_SZ; p += 1024) {
        const int m = p / OUT_SZ, o = p % OUT_SZ;
        const int nn = base + m;
        if (nn < N_WIN) {
            float acc = linB[o];
            for (int k = 0; k < H_SZ; ++k)
                acc += featl[m][k] * linW[o * H_SZ + k];
            out[nn * OUT_SZ + o] = acc;
            const float lev = levels[nn + WIN_SZ];
            const int tt = nn + WIN_SZ + o;
            out[N_WIN * OUT_SZ + nn * OUT_SZ + o] =
                logf(x[tt] / (lev * wsv[tt])) + noise_lab[nn * OUT_SZ + o];
        }
    }
    if (blockIdx.x == 0 && tid == 0)
        out[2 * N_WIN * OUT_SZ] = 0.0f;   // level_var_loss
}

// ---------------------------------------------------------------------------
extern "C" void kernel_launch(void* const* d_in, const int* in_sizes, int n_in,
                              void* d_out, int out_size, void* d_ws, size_t ws_size,
                              hipStream_t stream) {
    const float* x           = (const float*)d_in[0];
    const float* lvl_raw     = (const float*)d_in[1];
    const float* seas_raw    = (const float*)d_in[2];
    const float* seas_params = (const float*)d_in[3];
    const float* noise_in    = (const float*)d_in[4];
    const float* noise_lab   = (const float*)d_in[5];
    const float* Wx0         = (const float*)d_in[6];
    const float* Wh0         = (const float*)d_in[7];
    const float* b0v         = (const float*)d_in[8];
    const float* Wx1         = (const float*)d_in[9];
    const float* Wh1         = (const float*)d_in[10];
    const float* b1v         = (const float*)d_in[11];
    const float* tanhW       = (const float*)d_in[12];
    const float* tanhB       = (const float*)d_in[13];
    const float* linW        = (const float*)d_in[14];
    const float* linB        = (const float*)d_in[15];
    float* out = (float*)d_out;

    // workspace layout (floats; pw0/pw1 16B-aligned by construction)
    float* wsf    = (float*)d_ws;
    float* levels = wsf;                                   // 1024
    float* wsv    = levels + T_LEN;                        // 1024
    float* tanhWT = wsv + T_LEN;                           // 16384
    uint4* pw0    = (uint4*)(tanhWT + H_SZ * H_SZ);        // 8192 uint4
    uint4* pw1    = pw0 + 8192;                            // 16384 uint4

    hipLaunchKernelGGL(pre_kernel, dim3(161), dim3(256), 0, stream,
                       x, lvl_raw, seas_raw, seas_params, Wh0, Wx1, Wh1, tanhW,
                       levels, wsv, pw0, pw1, tanhWT);
    hipLaunchKernelGGL(fused_kernel, dim3(NBLK), dim3(1024), 0, stream,
                       x, levels, wsv, noise_in, Wx0, b0v, b1v, pw0, pw1,
                       tanhWT, tanhB, linW, linB, noise_lab, out);
}

// Round 10
// 883.376 us; speedup vs baseline: 1.6052x; 1.6052x over previous
//
#include <hip/hip_runtime.h>
#include <math.h>

#define T_LEN   1024
#define S_SEAS  168
#define H_SZ    128
#define G_SZ    512   // 4*H
#define WIN_SZ  168
#define OUT_SZ  24
#define N_WIN   833
#define BB      16
#define NBLK    ((N_WIN + BB - 1) / BB)   // 53

typedef __attribute__((ext_vector_type(8))) __bf16 bf16x8;
typedef __attribute__((ext_vector_type(4))) float  f32x4;

__device__ __forceinline__ float fsig(float x) {
    return __fdividef(1.0f, 1.0f + __expf(-x));
}
__device__ __forceinline__ float ftanh(float x) {
    return 1.0f - __fdividef(2.0f, __expf(2.0f * x) + 1.0f);
}

// Counted-wait barrier: order LDS only; globals ride across (T3/T4).
#define LDS_BARRIER()                                        \
    do {                                                     \
        asm volatile("s_waitcnt lgkmcnt(0)" ::: "memory");   \
        __builtin_amdgcn_s_barrier();                        \
    } while (0)

// ---------------------------------------------------------------------------
// Kernel 1: parallel ES scan (block 0) + weight prep (blocks 1..160).
// Scan parallelization: within a 168-step chunk, every seasonal factor
// w_i = buf[i mod 168] is already final (written 168 steps earlier), so
// level_i = t_i + ca*level_{i-1} with t_i = a*x_i/w_i known -> first-order
// linear recurrence -> Hillis-Steele scan (8 rounds/chunk, 7 chunks).
// ---------------------------------------------------------------------------
__global__ __launch_bounds__(256) void pre_kernel(
    const float* __restrict__ x,
    const float* __restrict__ lvl_raw,
    const float* __restrict__ seas_raw,
    const float* __restrict__ seas_params,
    const float* __restrict__ Wh0,
    const float* __restrict__ Wx1,
    const float* __restrict__ Wh1,
    const float* __restrict__ tanhW,
    float* __restrict__ levels,
    float* __restrict__ wsv,
    uint4* __restrict__ pw0,
    uint4* __restrict__ pw1,
    float* __restrict__ tanhWT) {
    const int t = threadIdx.x;

    if (blockIdx.x == 0) {
        __shared__ float xl[T_LEN];
        __shared__ float buf[S_SEAS];
        __shared__ float Ss[S_SEAS], Fs[S_SEAS];
        __shared__ float levCarry;
        for (int i = t; i < T_LEN; i += 256) xl[i] = x[i];
        for (int i = t; i < S_SEAS; i += 256) {
            const float w = expf(seas_params[i]);
            buf[i] = w;
            wsv[i] = w;
        }
        __syncthreads();
        const float a  = 1.0f / (1.0f + expf(-lvl_raw[0]));
        const float g  = 1.0f / (1.0f + expf(-seas_raw[0]));
        const float ca = 1.0f - a, cg = 1.0f - g;
        if (t == 0) {
            levCarry = __fdividef(xl[0], buf[0]);
            levels[0] = levCarry;
            wsv[S_SEAS] = buf[0];   // ws_full[168] = w_init[0]
        }
        __syncthreads();

        int cs = 1;
        while (cs < T_LEN) {
            const int L = min(S_SEAS, T_LEN - cs);
            float w = 0.0f;
            if (t < L) {
                const int i = cs + t;
                w = buf[i % S_SEAS];                 // final since step i-168
                Ss[t] = __fdividef(a * xl[i], w);    // t_i
                Fs[t] = ca;
            }
            __syncthreads();
            for (int d = 1; d < L; d <<= 1) {
                float sp = 0.0f, fp = 0.0f;
                const bool act = (t < L) && (t >= d);
                if (act) { sp = Ss[t - d]; fp = Fs[t - d]; }
                __syncthreads();
                if (act) {
                    Ss[t] = Ss[t] + Fs[t] * sp;
                    Fs[t] = Fs[t] * fp;
                }
                __syncthreads();
            }
            if (t < L) {
                const int i = cs + t;
                const float nl = Ss[t] + Fs[t] * levCarry;
                levels[i] = nl;
                const float nw = cg * w + __fdividef(g * xl[i], nl);
                buf[i % S_SEAS] = nw;
                if (i + S_SEAS < T_LEN) wsv[i + S_SEAS] = nw;
            }
            __syncthreads();
            if (t == 0) levCarry = Ss[L - 1] + Fs[L - 1] * levCarry;
            __syncthreads();
            cs += L;
        }
        return;
    }

    // ------- weight prep: pack MFMA B-frags (m92/m97 layout) -------
    const int idx = (blockIdx.x - 1) * 256 + t;
    auto bfr = [](float f) -> unsigned int {   // fp32 -> bf16 (RNE)
        union { float f; unsigned int u; } v; v.f = f;
        return ((v.u + 0x7FFFu + ((v.u >> 16) & 1u)) >> 16) & 0xFFFFu;
    };
    if (idx < 8192) {                       // pw0: Wh0, 128 frags (8w x 4ns x 4kt)
        const int l = idx & 63, f = idx >> 6;
        const int kt = f & 3, ns = (f >> 2) & 3, w = f >> 4;
        const int g = ns * 128 + w * 16 + (l & 15);
        const int kb = kt * 32 + (l >> 4) * 8;
        const float* s = Wh0 + g * H_SZ + kb;
        uint4 o;
        unsigned int* po = &o.x;
        for (int p = 0; p < 4; ++p) po[p] = bfr(s[2 * p]) | (bfr(s[2 * p + 1]) << 16);
        pw0[idx] = o;
    } else if (idx < 8192 + 16384) {        // pw1: [Wx1 (kt<4); Wh1 (kt>=4)]
        const int j = idx - 8192;
        const int l = j & 63, f = j >> 6;
        const int kt = f & 7, ns = (f >> 3) & 3, w = f >> 5;
        const int g = ns * 128 + w * 16 + (l & 15);
        const float* srcm = (kt < 4) ? Wx1 : Wh1;
        const int kb = (kt & 3) * 32 + (l >> 4) * 8;
        const float* s = srcm + g * H_SZ + kb;
        uint4 o;
        unsigned int* po = &o.x;
        for (int p = 0; p < 4; ++p) po[p] = bfr(s[2 * p]) | (bfr(s[2 * p + 1]) << 16);
        pw1[j] = o;
    } else if (idx < 8192 + 16384 + 16384) {  // tanh_W transpose (fp32)
        const int j = idx - 8192 - 16384;
        const int m = j >> 7, k = j & 127;
        tanhWT[k * H_SZ + m] = tanhW[j];
    }
}

// ---------------------------------------------------------------------------
// Kernel 2: fused 2-layer LSTM + window + head + labels (wave-specialized).
// 16 waves (4/SIMD via waves_per_eu(4,4) -> 128 unified regs/lane):
//   waves 0-7 : layer-0 step it   (Wh0 in 64 AGPR)
//   waves 8-15: layer-1 step it-1 (Wh1 in 64 AGPR; Wx1 from LDS per step)
// h0/h1 handoff via LDS double-buffers; no global hs0; 1 counted barrier/it.
// LDS: Wx1 128K + h0 8K + h1 8K + xls 10.5K = 154.5K (epilogue aliases).
// ---------------------------------------------------------------------------
__global__
__attribute__((amdgpu_flat_work_group_size(1024, 1024), amdgpu_waves_per_eu(4, 4)))
void fused_kernel(
    const float* __restrict__ x,
    const float* __restrict__ levels,
    const float* __restrict__ wsv,
    const float* __restrict__ noise_in,
    const float* __restrict__ Wx0,
    const float* __restrict__ b0v,
    const float* __restrict__ b1v,
    const uint4* __restrict__ pw0,
    const uint4* __restrict__ pw1,
    const float* __restrict__ tanhWT,
    const float* __restrict__ tanhB,
    const float* __restrict__ linW,
    const float* __restrict__ linB,
    const float* __restrict__ noise_lab,
    float* __restrict__ out) {
    __shared__ __align__(16) char smem[158208];
    char* const wx1s = smem;                       // 131072B packed Wx1 frags
    char* const hb0  = smem + 131072;              // 8192B h0 dbuf (swizzled)
    char* const hb1  = smem + 139264;              // 8192B h1 dbuf
    float* const xls = (float*)(smem + 147456);    // [168][16] f32
    float* const hfl   = (float*)(smem + 147456);  // alias: final h1 [16][129]
    float* const featl = (float*)smem;             // alias: feat [16][128]

    const int tid  = threadIdx.x;
    const int wv   = tid >> 6;            // 0..15
    const int lane = tid & 63;
    const int cc   = lane & 15;
    const int kl   = lane >> 4;
    const int base = blockIdx.x * BB;
    const bool isL1 = (wv >= 8);
    const int w    = wv & 7;

    // stage x (fused log-deseasonalization + noise) for the 16 windows
    for (int i = tid; i < WIN_SZ * BB; i += 1024) {
        const int t = i >> 4, m = i & 15;
        const int nn = base + m;
        float v = 0.0f;
        if (nn < N_WIN) {
            const float lev = levels[nn + WIN_SZ];
            const int tt = nn + t;
            v = logf(x[tt] / (lev * wsv[tt])) + noise_in[nn * WIN_SZ + t];
        }
        xls[t * 16 + m] = v;
    }
    for (int i = tid; i < 2 * 16 * 128; i += 1024) {
        ((__bf16*)hb0)[i] = (__bf16)0.0f;
        ((__bf16*)hb1)[i] = (__bf16)0.0f;
    }
    // stage Wx1 frags into LDS (frag f=(w*4+ns)*4+kt at wx1s + f*1024)
    for (int i = tid; i < 8192; i += 1024) {
        const int l = i & 63, f = i >> 6;
        const int kt = f & 3, nsw = f >> 2;        // nsw = w*4+ns
        ((uint4*)wx1s)[i] = pw1[(nsw * 8 + kt) * 64 + l];
    }

    // role weights -> 64 AGPRs: l0 = Wh0 frags, l1 = Wh1 frags
    const bf16x8* psrc = (const bf16x8*)(isL1 ? pw1 : pw0);
    bf16x8 wW[4][4];
#pragma unroll
    for (int ns = 0; ns < 4; ++ns)
#pragma unroll
        for (int kt = 0; kt < 4; ++kt) {
            const int fi = isL1 ? ((w * 4 + ns) * 8 + kt + 4)
                                : ((w * 4 + ns) * 4 + kt);
            wW[ns][kt] = psrc[fi * 64 + lane];
        }
#pragma unroll
    for (int ns = 0; ns < 4; ++ns)
#pragma unroll
        for (int kt = 0; kt < 4; ++kt)
            asm("" : "+a"(wW[ns][kt]));   // pin in AGPR class (one-time)

    float br[4], wx0r[4];
#pragma unroll
    for (int ns = 0; ns < 4; ++ns) {
        const int g = ns * 128 + w * 16 + cc;
        br[ns]   = isL1 ? b1v[g] : b0v[g];
        wx0r[ns] = isL1 ? 0.0f : Wx0[g];
    }
    float cr[4] = {0.f, 0.f, 0.f, 0.f};

    // loop-invariant swizzled LDS byte offsets
    int rdA[4], wrA[4];
#pragma unroll
    for (int kt = 0; kt < 4; ++kt)
        rdA[kt] = cc * 256 + ((kt * 64 + kl * 16) ^ ((cc & 7) << 4));
#pragma unroll
    for (int r = 0; r < 4; ++r) {
        const int row = kl * 4 + r;
        wrA[r] = row * 256 + (((w * 16 + cc) * 2) ^ ((row & 7) << 4));
    }
    const int wxB = w * 16384 + lane * 16;   // per-lane Wx1 LDS base
    __syncthreads();   // one-time full barrier after init

    // Slot convention: h at time t lives in slot t&1 of its buffer.
#define FUSED_STEP(IT, P)                                                      \
    {                                                                          \
        const int it_ = (IT);                                                  \
        if (!isL1) {                                                           \
            if (it_ < WIN_SZ) {                                                \
                const float4 xt_ = *(const float4*)&xls[it_ * 16 + kl * 4];    \
                f32x4 a0_, a1_, a2_, a3_;                                      \
                _Pragma("unroll")                                              \
                for (int r = 0; r < 4; ++r) {                                  \
                    const float xr_ = (r == 0) ? xt_.x : (r == 1) ? xt_.y      \
                                     : (r == 2) ? xt_.z : xt_.w;               \
                    a0_[r] = br[0] + wx0r[0] * xr_;                            \
                    a1_[r] = br[1] + wx0r[1] * xr_;                            \
                    a2_[r] = br[2] + wx0r[2] * xr_;                            \
                    a3_[r] = br[3] + wx0r[3] * xr_;                            \
                }                                                              \
                _Pragma("unroll")                                              \
                for (int kt = 0; kt < 4; ++kt) {                               \
                    const bf16x8 af_ = *(const bf16x8*)(hb0 + ((P) ^ 1) * 4096 + rdA[kt]); \
                    a0_ = __builtin_amdgcn_mfma_f32_16x16x32_bf16(af_, wW[0][kt], a0_, 0, 0, 0); \
                    a1_ = __builtin_amdgcn_mfma_f32_16x16x32_bf16(af_, wW[1][kt], a1_, 0, 0, 0); \
                    a2_ = __builtin_amdgcn_mfma_f32_16x16x32_bf16(af_, wW[2][kt], a2_, 0, 0, 0); \
                    a3_ = __builtin_amdgcn_mfma_f32_16x16x32_bf16(af_, wW[3][kt], a3_, 0, 0, 0); \
                }                                                              \
                _Pragma("unroll")                                              \
                for (int r = 0; r < 4; ++r) {                                  \
                    const float ig_ = fsig(a0_[r]);                            \
                    const float fg_ = fsig(a1_[r]);                            \
                    const float gg_ = ftanh(a2_[r]);                           \
                    const float og_ = fsig(a3_[r]);                            \
                    const float c_  = fg_ * cr[r] + ig_ * gg_;                 \
                    cr[r] = c_;                                                \
                    *(__bf16*)(hb0 + (P) * 4096 + wrA[r]) =                    \
                        (__bf16)(og_ * ftanh(c_));                             \
                }                                                              \
            }                                                                  \
        } else {                                                               \
            if (it_ >= 1) {                                                    \
                const int t1_ = it_ - 1;                                       \
                f32x4 a0_ = {br[0], br[0], br[0], br[0]};                      \
                f32x4 a1_ = {br[1], br[1], br[1], br[1]};                      \
                f32x4 a2_ = {br[2], br[2], br[2], br[2]};                      \
                f32x4 a3_ = {br[3], br[3], br[3], br[3]};                      \
                _Pragma("unroll")                                              \
                for (int kt = 0; kt < 4; ++kt) {  /* Wx1 on h0[t1]: B from LDS */ \
                    const bf16x8 af_ = *(const bf16x8*)(hb0 + ((P) ^ 1) * 4096 + rdA[kt]); \
                    const bf16x8 b0_ = *(const bf16x8*)(wx1s + wxB + 0 * 4096 + kt * 1024); \
                    const bf16x8 b1_ = *(const bf16x8*)(wx1s + wxB + 1 * 4096 + kt * 1024); \
                    const bf16x8 b2_ = *(const bf16x8*)(wx1s + wxB + 2 * 4096 + kt * 1024); \
                    const bf16x8 b3_ = *(const bf16x8*)(wx1s + wxB + 3 * 4096 + kt * 1024); \
                    a0_ = __builtin_amdgcn_mfma_f32_16x16x32_bf16(af_, b0_, a0_, 0, 0, 0); \
                    a1_ = __builtin_amdgcn_mfma_f32_16x16x32_bf16(af_, b1_, a1_, 0, 0, 0); \
                    a2_ = __builtin_amdgcn_mfma_f32_16x16x32_bf16(af_, b2_, a2_, 0, 0, 0); \
                    a3_ = __builtin_amdgcn_mfma_f32_16x16x32_bf16(af_, b3_, a3_, 0, 0, 0); \
                }                                                              \
                _Pragma("unroll")                                              \
                for (int kt = 0; kt < 4; ++kt) {  /* Wh1 on h1[t1-1]: B in AGPR */ \
                    const bf16x8 af_ = *(const bf16x8*)(hb1 + (P) * 4096 + rdA[kt]); \
                    a0_ = __builtin_amdgcn_mfma_f32_16x16x32_bf16(af_, wW[0][kt], a0_, 0, 0, 0); \
                    a1_ = __builtin_amdgcn_mfma_f32_16x16x32_bf16(af_, wW[1][kt], a1_, 0, 0, 0); \
                    a2_ = __builtin_amdgcn_mfma_f32_16x16x32_bf16(af_, wW[2][kt], a2_, 0, 0, 0); \
                    a3_ = __builtin_amdgcn_mfma_f32_16x16x32_bf16(af_, wW[3][kt], a3_, 0, 0, 0); \
                }                                                              \
                _Pragma("unroll")                                              \
                for (int r = 0; r < 4; ++r) {                                  \
                    const float ig_ = fsig(a0_[r]);                            \
                    const float fg_ = fsig(a1_[r]);                            \
                    const float gg_ = ftanh(a2_[r]);                           \
                    const float og_ = fsig(a3_[r]);                            \
                    const float c_  = fg_ * cr[r] + ig_ * gg_;                 \
                    cr[r] = c_;                                                \
                    const float hv_ = og_ * ftanh(c_);                         \
                    if (t1_ == WIN_SZ - 1) {                                   \
                        hfl[(kl * 4 + r) * 129 + w * 16 + cc] = hv_;           \
                    } else {                                                   \
                        *(__bf16*)(hb1 + ((P) ^ 1) * 4096 + wrA[r]) = (__bf16)hv_; \
                    }                                                          \
                }                                                              \
            }                                                                  \
        }                                                                      \
        LDS_BARRIER();                                                         \
    }

    for (int tp = 0; tp < WIN_SZ / 2; ++tp) {
        FUSED_STEP(2 * tp, 0)
        FUSED_STEP(2 * tp + 1, 1)
    }
    FUSED_STEP(WIN_SZ, 0)   // it=168: l1 finishes t1=167 -> hfl
#undef FUSED_STEP

    // ---- epilogue: feat = tanh(h @ tanhW^T + tanhB) ----
    for (int p = tid; p < BB * H_SZ; p += 1024) {
        const int m = p >> 7, u = p & 127;
        float acc = tanhB[u];
        for (int k = 0; k < H_SZ; ++k)
            acc += hfl[m * 129 + k] * tanhWT[k * H_SZ + u];
        featl[m * 128 + u] = tanhf(acc);
    }
    LDS_BARRIER();

    // ---- out = feat @ linW^T + linB; labels ----
    for (int p = tid; p < BB * OUT_SZ; p += 1024) {
        const int m = p / OUT_SZ, o = p % OUT_SZ;
        const int nn = base + m;
        if (nn < N_WIN) {
            float acc = linB[o];
            for (int k = 0; k < H_SZ; ++k)
                acc += featl[m * 128 + k] * linW[o * H_SZ + k];
            out[nn * OUT_SZ + o] = acc;
            const float lev = levels[nn + WIN_SZ];
            const int tt = nn + WIN_SZ + o;
            out[N_WIN * OUT_SZ + nn * OUT_SZ + o] =
                logf(x[tt] / (lev * wsv[tt])) + noise_lab[nn * OUT_SZ + o];
        }
    }
    if (blockIdx.x == 0 && tid == 0)
        out[2 * N_WIN * OUT_SZ] = 0.0f;   // level_var_loss
}

// ---------------------------------------------------------------------------
extern "C" void kernel_launch(void* const* d_in, const int* in_sizes, int n_in,
                              void* d_out, int out_size, void* d_ws, size_t ws_size,
                              hipStream_t stream) {
    const float* x           = (const float*)d_in[0];
    const float* lvl_raw     = (const float*)d_in[1];
    const float* seas_raw    = (const float*)d_in[2];
    const float* seas_params = (const float*)d_in[3];
    const float* noise_in    = (const float*)d_in[4];
    const float* noise_lab   = (const float*)d_in[5];
    const float* Wx0         = (const float*)d_in[6];
    const float* Wh0         = (const float*)d_in[7];
    const float* b0v         = (const float*)d_in[8];
    const float* Wx1         = (const float*)d_in[9];
    const float* Wh1         = (const float*)d_in[10];
    const float* b1v         = (const float*)d_in[11];
    const float* tanhW       = (const float*)d_in[12];
    const float* tanhB       = (const float*)d_in[13];
    const float* linW        = (const float*)d_in[14];
    const float* linB        = (const float*)d_in[15];
    float* out = (float*)d_out;

    // workspace layout (floats; pw0/pw1 16B-aligned by construction)
    float* wsf    = (float*)d_ws;
    float* levels = wsf;                                   // 1024
    float* wsv    = levels + T_LEN;                        // 1024
    float* tanhWT = wsv + T_LEN;                           // 16384
    uint4* pw0    = (uint4*)(tanhWT + H_SZ * H_SZ);        // 8192 uint4
    uint4* pw1    = pw0 + 8192;                            // 16384 uint4

    hipLaunchKernelGGL(pre_kernel, dim3(161), dim3(256), 0, stream,
                       x, lvl_raw, seas_raw, seas_params, Wh0, Wx1, Wh1, tanhW,
                       levels, wsv, pw0, pw1, tanhWT);
    hipLaunchKernelGGL(fused_kernel, dim3(NBLK), dim3(1024), 0, stream,
                       x, levels, wsv, noise_in, Wx0, b0v, b1v, pw0, pw1,
                       tanhWT, tanhB, linW, linB, noise_lab, out);
}